// Round 3
// baseline (118.491 us; speedup 1.0000x reference)
//
#include <hip/hip_runtime.h>

#define N_IN 59
#define N_VALUES 12
#define BLOCK 256
#define WTILE 64                      // rows per wave
#define TILE_FLOATS (WTILE * N_IN)    // 3776 floats = 944 float4 per wave tile
#define TILE_F4 (TILE_FLOATS / 4)     // 944

// Pre-kernel: transpose W [12][59] -> Wt [59][12] in d_ws.
// Wt rows are 48B -> every row 16B-aligned for float4 broadcast reads.
__global__ void transpose_w_kernel(const float* __restrict__ W,
                                   float* __restrict__ Wt) {
    int i = blockIdx.x * 256 + threadIdx.x;
    if (i < N_IN * N_VALUES) {
        int v = i / N_IN;
        int j = i - v * N_IN;
        Wt[j * N_VALUES + v] = W[i];
    }
}

__global__ __launch_bounds__(BLOCK, 2) void value_model_kernel(
    const float* __restrict__ act,    // [B, 59]
    const int*   __restrict__ cards,  // [B, 4, 3] int32
    const float* __restrict__ Wt,     // [59][12] transposed (in ws)
    const float* __restrict__ bias,   // [12]
    float* __restrict__ out,          // [B, 4]
    int B)
{
    // Wave-private act tiles: no __syncthreads anywhere -> waves stream
    // independently, memory issue stays continuous (no barrier bunching).
    __shared__ float aLds[4 * TILE_FLOATS];      // 60416 B, flat stride-59 rows
    __shared__ float fvLds[N_VALUES][BLOCK];     // 12288 B, lane-private columns

    const int tid  = threadIdx.x;
    const int wave = tid >> 6;
    const int lane = tid & 63;
    const long waveRowBase = (long)blockIdx.x * BLOCK + wave * WTILE;
    if (waveRowBase >= B) return;                // safe: no barriers used
    const long row = waveRowBase + lane;

    // Issue cards loads early (independent of everything else).
    int4 c0 = {0,0,0,0}, c1 = {0,0,0,0}, c2 = {0,0,0,0};
    if (row < B) {
        const int4* cp = (const int4*)(cards + row * 12);
        c0 = cp[0]; c1 = cp[1]; c2 = cp[2];
    }

    // Stage this wave's 64x59 act tile: coalesced float4, 15 per lane.
    // Tile base = waveRowBase*59*4 B; waveRowBase%64==0 -> 16B-aligned.
    float* a = aLds + wave * TILE_FLOATS;
    {
        const int nf = (int)((B - waveRowBase) < WTILE
                             ? (B - waveRowBase) * N_IN : TILE_FLOATS);
        const int nf4 = nf >> 2;                 // 944 for full tiles
        const float4* src4 = (const float4*)(act + waveRowBase * N_IN);
        float4* dst4 = (float4*)a;
        #pragma unroll
        for (int q = 0; q < 15; ++q) {
            int idx = lane + q * 64;
            if (idx < nf4) dst4[idx] = src4[idx];
        }
        // (compiler inserts vmcnt between load and ds_write via reg dep)
    }
    // Cross-lane RAW through LDS within one wave: drain LDS ops, fence compiler.
    asm volatile("s_waitcnt lgkmcnt(0)" ::: "memory");
    __builtin_amdgcn_wave_barrier();

    float acc[N_VALUES];
    {   // bias: uniform loads (scalar-promoted)
        #pragma unroll
        for (int v = 0; v < N_VALUES; ++v) acc[v] = bias[v];
    }

    // Main dot: act from LDS (stride 59, odd -> conflict-free b32),
    // W from global uniform float4 (L1/K$-cached, off the LDS pipe).
    {
        const float* arow = a + lane * N_IN;
        const float4* wt4 = (const float4*)Wt;
        #pragma unroll 2
        for (int j = 0; j < N_IN; ++j) {
            float x  = arow[j];
            float4 w0 = wt4[j * 3 + 0];
            float4 w1 = wt4[j * 3 + 1];
            float4 w2 = wt4[j * 3 + 2];
            acc[0]  = fmaf(x, w0.x, acc[0]);
            acc[1]  = fmaf(x, w0.y, acc[1]);
            acc[2]  = fmaf(x, w0.z, acc[2]);
            acc[3]  = fmaf(x, w0.w, acc[3]);
            acc[4]  = fmaf(x, w1.x, acc[4]);
            acc[5]  = fmaf(x, w1.y, acc[5]);
            acc[6]  = fmaf(x, w1.z, acc[6]);
            acc[7]  = fmaf(x, w1.w, acc[7]);
            acc[8]  = fmaf(x, w2.x, acc[8]);
            acc[9]  = fmaf(x, w2.y, acc[9]);
            acc[10] = fmaf(x, w2.z, acc[10]);
            acc[11] = fmaf(x, w2.w, acc[11]);
        }
    }

    // Runtime-indexed gather via lane-private LDS column (no scratch spill).
    #pragma unroll
    for (int v = 0; v < N_VALUES; ++v) fvLds[v][tid] = acc[v];
    // same lane, same addresses -> in-order LDS, no barrier needed

    float4 o;
    o.x = fvLds[c0.x][tid] + fvLds[c0.y][tid] + fvLds[c0.z][tid];
    o.y = fvLds[c0.w][tid] + fvLds[c1.x][tid] + fvLds[c1.y][tid];
    o.z = fvLds[c1.z][tid] + fvLds[c1.w][tid] + fvLds[c2.x][tid];
    o.w = fvLds[c2.y][tid] + fvLds[c2.z][tid] + fvLds[c2.w][tid];

    if (row < B) *(float4*)(out + row * 4) = o;
}

extern "C" void kernel_launch(void* const* d_in, const int* in_sizes, int n_in,
                              void* d_out, int out_size, void* d_ws, size_t ws_size,
                              hipStream_t stream) {
    const float* act   = (const float*)d_in[0];
    const int*   cards = (const int*)d_in[1];
    const float* W     = (const float*)d_in[2];
    const float* bias  = (const float*)d_in[3];
    float* out = (float*)d_out;
    float* Wt  = (float*)d_ws;        // 708 floats = 2832 B scratch

    const int B = in_sizes[0] / N_IN;  // 1,000,000

    transpose_w_kernel<<<3, 256, 0, stream>>>(W, Wt);

    const int grid = (B + BLOCK - 1) / BLOCK;
    value_model_kernel<<<grid, BLOCK, 0, stream>>>(act, cards, Wt, bias, out, B);
}

// Round 4
// 95.697 us; speedup vs baseline: 1.2382x; 1.2382x over previous
//
#include <hip/hip_runtime.h>

#define N_IN 59
#define N_VALUES 12
#define BLOCK 256
#define RPT 4                         // rows per thread (4*59*4B = 944B, 16B-aligned)

// Pre-kernel: transpose W [12][59] -> Wt [59][12] in d_ws.
// Wt rows are 48B -> 16B-aligned for s_load_dwordx4 broadcast reads.
__global__ void transpose_w_kernel(const float* __restrict__ W,
                                   float* __restrict__ Wt) {
    int i = blockIdx.x * 256 + threadIdx.x;
    if (i < N_IN * N_VALUES) {
        int v = i / N_IN;
        int j = i - v * N_IN;
        Wt[j * N_VALUES + v] = W[i];
    }
}

__global__ __launch_bounds__(BLOCK) void value_model_kernel(
    const float* __restrict__ act,    // [B, 59]
    const int*   __restrict__ cards,  // [B, 4, 3] int32
    const float* __restrict__ Wt,     // [59][12] transposed (in ws)
    const float* __restrict__ bias,   // [12]
    float* __restrict__ out,          // [B, 4]
    int nThreads)                     // B / RPT = 250,000
{
    // Only LDS use: runtime-indexed gather at the end. Lane-private column,
    // bank = tid%32 -> conflict-free. NOT touched in the main loop, so no
    // lgkmcnt interaction with the SMEM W loads there.
    __shared__ float fvLds[N_VALUES][BLOCK];

    const int tid = threadIdx.x;
    int g = blockIdx.x * BLOCK + tid;
    // Tail: clamp instead of branch. Last 112 threads duplicate the final
    // row-block's work and write identical values -> deterministic, and the
    // kernel stays 100% branch-free so W/bias loads scalarize to s_load.
    if (g >= nThreads) g = nThreads - 1;

    // bias via uniform float4 loads -> s_load_dwordx4
    const float4* bias4 = (const float4*)bias;
    const float4 b0 = bias4[0], b1 = bias4[1], b2 = bias4[2];

    float acc[RPT][N_VALUES];
    #pragma unroll
    for (int r = 0; r < RPT; ++r) {
        acc[r][0] = b0.x; acc[r][1] = b0.y; acc[r][2]  = b0.z; acc[r][3]  = b0.w;
        acc[r][4] = b1.x; acc[r][5] = b1.y; acc[r][6]  = b1.z; acc[r][7]  = b1.w;
        acc[r][8] = b2.x; acc[r][9] = b2.y; acc[r][10] = b2.z; acc[r][11] = b2.w;
    }

    // 4 rows = 236 floats = 59 float4, base byte = g*944 (16B-aligned).
    // Fully unrolled: (row, j) of every element is a compile-time constant,
    // so acc indexing is static (no scratch) and W addresses are uniform.
    const float4* A4 = (const float4*)(act + (long)g * (RPT * N_IN));
    const float4* wt4 = (const float4*)Wt;   // [59][3] float4, uniform -> s_load
    #pragma unroll
    for (int k = 0; k < 59; ++k) {
        const float4 x = A4[k];
        #pragma unroll
        for (int e = 0; e < 4; ++e) {
            const int flat = 4 * k + e;
            const int r = flat / N_IN;        // compile-time
            const int j = flat - r * N_IN;    // compile-time
            const float xe = (e == 0) ? x.x : (e == 1) ? x.y : (e == 2) ? x.z : x.w;
            const float4 w0 = wt4[j * 3 + 0];
            const float4 w1 = wt4[j * 3 + 1];
            const float4 w2 = wt4[j * 3 + 2];
            acc[r][0]  = fmaf(xe, w0.x, acc[r][0]);
            acc[r][1]  = fmaf(xe, w0.y, acc[r][1]);
            acc[r][2]  = fmaf(xe, w0.z, acc[r][2]);
            acc[r][3]  = fmaf(xe, w0.w, acc[r][3]);
            acc[r][4]  = fmaf(xe, w1.x, acc[r][4]);
            acc[r][5]  = fmaf(xe, w1.y, acc[r][5]);
            acc[r][6]  = fmaf(xe, w1.z, acc[r][6]);
            acc[r][7]  = fmaf(xe, w1.w, acc[r][7]);
            acc[r][8]  = fmaf(xe, w2.x, acc[r][8]);
            acc[r][9]  = fmaf(xe, w2.y, acc[r][9]);
            acc[r][10] = fmaf(xe, w2.z, acc[r][10]);
            acc[r][11] = fmaf(xe, w2.w, acc[r][11]);
        }
    }

    // Gather: reuse the small fv buffer sequentially per row (same lane,
    // same column -> in-order LDS, no barriers, no cross-thread traffic).
    const int4* cp = (const int4*)(cards + (long)g * (RPT * 12));  // byte g*192, aligned
    float* orow = out + (long)g * (RPT * 4);                       // byte g*64, aligned
    #pragma unroll
    for (int r = 0; r < RPT; ++r) {
        #pragma unroll
        for (int v = 0; v < N_VALUES; ++v) fvLds[v][tid] = acc[r][v];
        const int4 c0 = cp[3 * r + 0];
        const int4 c1 = cp[3 * r + 1];
        const int4 c2 = cp[3 * r + 2];
        float4 o;
        o.x = fvLds[c0.x][tid] + fvLds[c0.y][tid] + fvLds[c0.z][tid];
        o.y = fvLds[c0.w][tid] + fvLds[c1.x][tid] + fvLds[c1.y][tid];
        o.z = fvLds[c1.z][tid] + fvLds[c1.w][tid] + fvLds[c2.x][tid];
        o.w = fvLds[c2.y][tid] + fvLds[c2.z][tid] + fvLds[c2.w][tid];
        *(float4*)(orow + 4 * r) = o;
    }
}

extern "C" void kernel_launch(void* const* d_in, const int* in_sizes, int n_in,
                              void* d_out, int out_size, void* d_ws, size_t ws_size,
                              hipStream_t stream) {
    const float* act   = (const float*)d_in[0];
    const int*   cards = (const int*)d_in[1];
    const float* W     = (const float*)d_in[2];
    const float* bias  = (const float*)d_in[3];
    float* out = (float*)d_out;
    float* Wt  = (float*)d_ws;        // 708 floats = 2832 B scratch

    const int B = in_sizes[0] / N_IN;          // 1,000,000
    const int nThreads = B / RPT;              // 250,000 (B % 4 == 0)

    transpose_w_kernel<<<3, 256, 0, stream>>>(W, Wt);

    const int grid = (nThreads + BLOCK - 1) / BLOCK;   // 977
    value_model_kernel<<<grid, BLOCK, 0, stream>>>(act, cards, Wt, bias, out, nThreads);
}

// Round 5
// 55.826 us; speedup vs baseline: 2.1225x; 1.7142x over previous
//
#include <hip/hip_runtime.h>

#define N_IN 59
#define N_VALUES 12
#define BLOCK 256
#define WROWS 32                       // rows per wave
#define ROWS_PER_BLOCK 128             // 4 waves
#define TILE_F (WROWS * N_IN)          // 1888 floats per wave tile
#define TILE_STRIDE_F 1896             // +8 pad: frag reads touch idx up to 1892
#define FVW_STRIDE 17                  // [32][17] f32 per wave (bank-spread)

typedef __attribute__((ext_vector_type(4))) float  f32x4;
typedef __attribute__((ext_vector_type(8))) __bf16 bf16x8;

static __device__ __forceinline__ unsigned short f2bf_bits(float x) {
    return __builtin_bit_cast(unsigned short, (__bf16)x);
}

// Pre-kernel: bake W [12][59] into MFMA B-fragments, bf16, K padded to 64,
// N padded to 16. Layout: tab[h*64 + lane] = 8 bf16 (16B), where for
// mfma_f32_16x16x32_bf16 lane l holds B[k=(l>>4)*8+e][col=l&15] of K-half h.
__global__ void build_wfrag(const float* __restrict__ W,
                            unsigned short* __restrict__ tab) {
    int t = threadIdx.x;               // 0..127
    int h = t >> 6, l = t & 63;
    int v = l & 15, g = l >> 4;
    unsigned int words[4];
    #pragma unroll
    for (int p = 0; p < 4; ++p) {
        unsigned int lo, hi;
        {
            int k = h * 32 + g * 8 + 2 * p;
            float val = (k < N_IN && v < N_VALUES) ? W[v * N_IN + k] : 0.0f;
            lo = f2bf_bits(val);
        }
        {
            int k = h * 32 + g * 8 + 2 * p + 1;
            float val = (k < N_IN && v < N_VALUES) ? W[v * N_IN + k] : 0.0f;
            hi = f2bf_bits(val);
        }
        words[p] = lo | (hi << 16);
    }
    uint4 u = make_uint4(words[0], words[1], words[2], words[3]);
    *(uint4*)(tab + (size_t)t * 8) = u;
}

__global__ __launch_bounds__(BLOCK, 4) void value_model_kernel(
    const float* __restrict__ act,     // [B, 59]
    const int*   __restrict__ cards,   // [B, 4, 3] int32
    const unsigned short* __restrict__ wtab, // B-fragments (2*64*8 bf16)
    const float* __restrict__ bias,    // [12]
    float* __restrict__ out,           // [B, 4]
    int B)
{
    // Wave-private LDS; no __syncthreads anywhere -> waves stream freely.
    __shared__ float aLds[4 * TILE_STRIDE_F];          // 4 x 7584B act tiles
    __shared__ float fvLds[4 * WROWS * FVW_STRIDE];    // 4 x 2176B fv tiles

    const int tid  = threadIdx.x;
    const int wave = tid >> 6;
    const int lane = tid & 63;
    const long wbase = (long)blockIdx.x * ROWS_PER_BLOCK + wave * WROWS;
    if (wbase >= B) return;            // full-tile waves only (B % 32 == 0)

    float* tw = aLds  + wave * TILE_STRIDE_F;
    float* fw = fvLds + wave * (WROWS * FVW_STRIDE);

    // ---- B-fragments: W in 8 VGPRs, loaded once (lane-contiguous 16B) ----
    const bf16x8* tab8 = (const bf16x8*)wtab;
    bf16x8 bf0 = tab8[lane];
    bf16x8 bf1 = tab8[64 + lane];

    // bias lands on C columns: col = lane&15
    const int colA = lane & 15, gA = lane >> 4;
    float bv = (colA < N_VALUES) ? bias[colA] : 0.0f;
    f32x4 acc0 = {bv, bv, bv, bv};
    f32x4 acc1 = {bv, bv, bv, bv};

    // ---- Stage 32x59 f32 act tile: lane-CONTIGUOUS float4 (8 line-req/instr)
    {
        const float4* src = (const float4*)(act + wbase * N_IN); // 16B-aligned
        float4* dst = (float4*)tw;
        #pragma unroll
        for (int q = 0; q < 8; ++q) {
            int idx = lane + q * 64;
            if (idx < TILE_F / 4) dst[idx] = src[idx];           // 472 float4
        }
    }
    asm volatile("s_waitcnt lgkmcnt(0)" ::: "memory");
    __builtin_amdgcn_wave_barrier();

    // ---- MFMA: A[row=l&15][k=(l>>4)*8+e] from LDS (stride 59 words: odd ->
    // <=2 lanes/bank, b32 reads, no swizzle). Zero-pad k>=59 on the h=1,g=3 frag.
    #pragma unroll
    for (int h = 0; h < 2; ++h) {
        #pragma unroll
        for (int rb = 0; rb < 2; ++rb) {
            const float* p = tw + (rb * 16 + colA) * N_IN + h * 32 + gA * 8;
            bf16x8 a;
            #pragma unroll
            for (int e = 0; e < 8; ++e) {
                float v = p[e];
                if (h == 1) {
                    int k = 32 + gA * 8 + e;       // runtime (uniform per 16 lanes)
                    v = (k < N_IN) ? v : 0.0f;
                }
                a[e] = (__bf16)v;
            }
            if (rb == 0)
                acc0 = __builtin_amdgcn_mfma_f32_16x16x32_bf16(a, h ? bf1 : bf0, acc0, 0, 0, 0);
            else
                acc1 = __builtin_amdgcn_mfma_f32_16x16x32_bf16(a, h ? bf1 : bf0, acc1, 0, 0, 0);
        }
    }

    // ---- C -> fv LDS: C[row=(l>>4)*4+j][col=l&15], row-major [32][17] ----
    #pragma unroll
    for (int j = 0; j < 4; ++j) fw[(gA * 4 + j) * FVW_STRIDE + colA] = acc0[j];
    #pragma unroll
    for (int j = 0; j < 4; ++j) fw[(16 + gA * 4 + j) * FVW_STRIDE + colA] = acc1[j];
    asm volatile("s_waitcnt lgkmcnt(0)" ::: "memory");
    __builtin_amdgcn_wave_barrier();

    // ---- Gather epilogue: lane l handles row l>>1, half l&1 (2 cards) ----
    const int r    = lane >> 1;
    const int half = lane & 1;
    const long grow = wbase + r;
    const float* fv = fw + r * FVW_STRIDE;

    // cards: 3 x int2, 8B-aligned, lane-interleaved (~12 lines/instr)
    const int2* cp = (const int2*)(cards + grow * 12 + half * 6);
    int2 ca = cp[0], cb = cp[1], cc = cp[2];

    float s0 = fv[ca.x] + fv[ca.y] + fv[cb.x];
    float s1 = fv[cb.y] + fv[cc.x] + fv[cc.y];

    // out: lane-contiguous 8B stores (wave covers 512B contiguous)
    *(float2*)(out + grow * 4 + half * 2) = make_float2(s0, s1);
}

extern "C" void kernel_launch(void* const* d_in, const int* in_sizes, int n_in,
                              void* d_out, int out_size, void* d_ws, size_t ws_size,
                              hipStream_t stream) {
    const float* act   = (const float*)d_in[0];
    const int*   cards = (const int*)d_in[1];
    const float* W     = (const float*)d_in[2];
    const float* bias  = (const float*)d_in[3];
    float* out = (float*)d_out;
    unsigned short* wtab = (unsigned short*)d_ws;   // 2*64*8 bf16 = 2KB

    const int B = in_sizes[0] / N_IN;               // 1,000,000

    build_wfrag<<<1, 128, 0, stream>>>(W, wtab);

    const int grid = (B + ROWS_PER_BLOCK - 1) / ROWS_PER_BLOCK;   // 7813
    value_model_kernel<<<grid, BLOCK, 0, stream>>>(act, cards, wtab, bias, out, B);
}

// Round 6
// 52.320 us; speedup vs baseline: 2.2647x; 1.0670x over previous
//
#include <hip/hip_runtime.h>

#define N_IN 59
#define N_VALUES 12
#define BLOCK 256
#define WROWS 16                       // rows per wave (one 16x16 MFMA row-block)
#define ROWS_PER_BLOCK 64              // 4 waves
#define TILE_F (WROWS * N_IN)          // 944 floats per wave tile
#define TILE_F4 (TILE_F / 4)           // 236 float4
#define TILE_STRIDE_F 952              // +8 pad (zeroed; frag reads touch up to 948)
#define FV_STRIDE 12                   // [16][12] f32 per wave, 2-way banks on write

typedef __attribute__((ext_vector_type(4))) float  f32x4;
typedef __attribute__((ext_vector_type(8))) __bf16 bf16x8;

static __device__ __forceinline__ unsigned short f2bf_bits(float x) {
    return __builtin_bit_cast(unsigned short, (__bf16)x);
}

// Pre-kernel: bake W [12][59] into MFMA B-fragments, bf16, K padded to 64 with
// ZEROS (so k>=59 garbage in A contributes 0), N padded to 16.
// mfma_f32_16x16x32_bf16 B layout: lane l holds B[k=(l>>4)*8+e][col=l&15],
// K-half h in tab[h*64 + l]. (Verified empirically in round 5: absmax 0.0625.)
__global__ void build_wfrag(const float* __restrict__ W,
                            unsigned short* __restrict__ tab) {
    int t = threadIdx.x;               // 0..127
    int h = t >> 6, l = t & 63;
    int v = l & 15, g = l >> 4;
    unsigned int words[4];
    #pragma unroll
    for (int p = 0; p < 4; ++p) {
        unsigned int lo, hi;
        {
            int k = h * 32 + g * 8 + 2 * p;
            float val = (k < N_IN && v < N_VALUES) ? W[v * N_IN + k] : 0.0f;
            lo = f2bf_bits(val);
        }
        {
            int k = h * 32 + g * 8 + 2 * p + 1;
            float val = (k < N_IN && v < N_VALUES) ? W[v * N_IN + k] : 0.0f;
            hi = f2bf_bits(val);
        }
        words[p] = lo | (hi << 16);
    }
    uint4 u = make_uint4(words[0], words[1], words[2], words[3]);
    *(uint4*)(tab + (size_t)t * 8) = u;
}

__global__ __launch_bounds__(BLOCK, 8) void value_model_kernel(
    const float* __restrict__ act,     // [B, 59]
    const int*   __restrict__ cards,   // [B, 4, 3] int32
    const unsigned short* __restrict__ wtab, // B-fragments (2*64*8 bf16)
    const float* __restrict__ bias,    // [12]
    float* __restrict__ out,           // [B, 4]
    int B)
{
    // Wave-private LDS, no __syncthreads: waves stream independently.
    // 4*(3808 + 768) = 18304 B/block -> 8 blocks/CU -> 32 waves/CU.
    __shared__ float aLds[4 * TILE_STRIDE_F];
    __shared__ float fvLds[4 * WROWS * FV_STRIDE];

    const int tid  = threadIdx.x;
    const int wave = tid >> 6;
    const int lane = tid & 63;
    const long wbase = (long)blockIdx.x * ROWS_PER_BLOCK + wave * WROWS;
    // B == 1e6, ROWS_PER_BLOCK == 64, grid exact -> no bounds checks.

    float* tw = aLds  + wave * TILE_STRIDE_F;
    float* fw = fvLds + wave * (WROWS * FV_STRIDE);

    // ---- Issue async act staging FIRST (longest latency). 944 floats =
    // 236 float4: 3 full wave-wide global_load_lds + 44 lanes on the 4th.
    // LDS dest = wave-uniform base, HW scatters +lane*16 (linear layout).
    {
        const char* src = (const char*)(act + wbase * N_IN) + lane * 16;
        char* dst = (char*)tw;
        __builtin_amdgcn_global_load_lds(
            (const __attribute__((address_space(1))) void*)(src),
            (__attribute__((address_space(3))) void*)(dst), 16, 0, 0);
        __builtin_amdgcn_global_load_lds(
            (const __attribute__((address_space(1))) void*)(src + 1024),
            (__attribute__((address_space(3))) void*)(dst + 1024), 16, 0, 0);
        __builtin_amdgcn_global_load_lds(
            (const __attribute__((address_space(1))) void*)(src + 2048),
            (__attribute__((address_space(3))) void*)(dst + 2048), 16, 0, 0);
        if (lane < TILE_F4 - 192) {
            __builtin_amdgcn_global_load_lds(
                (const __attribute__((address_space(1))) void*)(src + 3072),
                (__attribute__((address_space(3))) void*)(dst + 3072), 16, 0, 0);
        }
    }

    // Zero the 8-word pad (undefined LDS would be a NaN risk in the over-read
    // region words 944..948; W's k>=59 columns are zero so products vanish).
    if (lane < TILE_STRIDE_F - TILE_F) tw[TILE_F + lane] = 0.0f;

    // ---- Independent register loads overlap the staging latency ----
    const bf16x8* tab8 = (const bf16x8*)wtab;
    bf16x8 bf0 = tab8[lane];
    bf16x8 bf1 = tab8[64 + lane];

    const int colA = lane & 15, gA = lane >> 4;
    float bv = (colA < N_VALUES) ? bias[colA] : 0.0f;

    const int r4 = lane >> 2, c4 = lane & 3;   // epilogue: row, card
    const long grow = wbase + r4;
    const int* cp = cards + grow * 12 + c4 * 3;
    const int i0 = cp[0], i1 = cp[1], i2 = cp[2];

    // ---- Wait staging (vm) + pad-zero (lgkm); wave-synchronous only ----
    asm volatile("s_waitcnt vmcnt(0) lgkmcnt(0)" ::: "memory");
    __builtin_amdgcn_wave_barrier();

    // ---- A-frags from LDS (stride-59 words, odd -> 2 lanes/bank = free),
    // f32->bf16 in-reg, 2 MFMAs over K halves ----
    f32x4 acc = {bv, bv, bv, bv};
    const float* p = tw + colA * N_IN + gA * 8;
    bf16x8 a0, a1;
    #pragma unroll
    for (int e = 0; e < 8; ++e) a0[e] = (__bf16)p[e];
    acc = __builtin_amdgcn_mfma_f32_16x16x32_bf16(a0, bf0, acc, 0, 0, 0);
    #pragma unroll
    for (int e = 0; e < 8; ++e) a1[e] = (__bf16)p[32 + e];
    acc = __builtin_amdgcn_mfma_f32_16x16x32_bf16(a1, bf1, acc, 0, 0, 0);

    // ---- C -> fv LDS: C[row=(l>>4)*4+j][col=l&15], [16][12] per wave ----
    if (colA < N_VALUES) {
        #pragma unroll
        for (int j = 0; j < 4; ++j)
            fw[(gA * 4 + j) * FV_STRIDE + colA] = acc[j];
    }
    asm volatile("s_waitcnt lgkmcnt(0)" ::: "memory");
    __builtin_amdgcn_wave_barrier();

    // ---- Gather epilogue: 1 card (3 indices) per lane, contiguous store ----
    const float* fv = fw + r4 * FV_STRIDE;
    out[grow * 4 + c4] = fv[i0] + fv[i1] + fv[i2];
}

extern "C" void kernel_launch(void* const* d_in, const int* in_sizes, int n_in,
                              void* d_out, int out_size, void* d_ws, size_t ws_size,
                              hipStream_t stream) {
    const float* act   = (const float*)d_in[0];
    const int*   cards = (const int*)d_in[1];
    const float* W     = (const float*)d_in[2];
    const float* bias  = (const float*)d_in[3];
    float* out = (float*)d_out;
    unsigned short* wtab = (unsigned short*)d_ws;   // 2*64*8 bf16 = 2KB

    const int B = in_sizes[0] / N_IN;               // 1,000,000

    build_wfrag<<<1, 128, 0, stream>>>(W, wtab);

    const int grid = B / ROWS_PER_BLOCK;            // 15625 exact
    value_model_kernel<<<grid, BLOCK, 0, stream>>>(act, cards, wtab, bias, out, B);
}

// Round 7
// 50.598 us; speedup vs baseline: 2.3418x; 1.0340x over previous
//
#include <hip/hip_runtime.h>

#define N_IN 59
#define N_VALUES 12
#define BLOCK 256
#define WROWS 16                        // rows per wave-tile (one 16x16 MFMA)
#define TILE_F (WROWS * N_IN)           // 944 floats per tile
#define TILE_BYTES (TILE_F * 4)         // 3776 B (16B-aligned per tile)
#define TILE_STRIDE_F 952               // +8 pad words (zeroed once)
#define FV_STRIDE 12                    // fv [16][12] per wave
#define WL_STRIDE 68                    // padded W image row stride (words)
#define WL_FLOATS (16 * WL_STRIDE)      // 1088 words; max read idx 15*68+63=1083
#define GRID 3125
#define WAVES 4
#define TOTWAVES (GRID * WAVES)         // 12500
#define TPW 5                           // tiles per wave: 12500*5 = 62500 = 1e6/16

typedef __attribute__((ext_vector_type(4))) float  f32x4;
typedef __attribute__((ext_vector_type(8))) __bf16 bf16x8;

// stage one 944-float tile into wave-private LDS via async DMA
// (dest = wave-uniform base + lane*16, linear; matches flat tile layout)
#define STAGE(tt)                                                              \
    do {                                                                       \
        const char* _s = (const char*)act + (long)(tt) * TILE_BYTES + lane * 16;\
        char* _d = (char*)tw;                                                  \
        __builtin_amdgcn_global_load_lds(                                      \
            (const __attribute__((address_space(1))) void*)(_s),               \
            (__attribute__((address_space(3))) void*)(_d), 16, 0, 0);          \
        __builtin_amdgcn_global_load_lds(                                      \
            (const __attribute__((address_space(1))) void*)(_s + 1024),        \
            (__attribute__((address_space(3))) void*)(_d + 1024), 16, 0, 0);   \
        __builtin_amdgcn_global_load_lds(                                      \
            (const __attribute__((address_space(1))) void*)(_s + 2048),        \
            (__attribute__((address_space(3))) void*)(_d + 2048), 16, 0, 0);   \
        if (lane < 44) {                                                       \
            __builtin_amdgcn_global_load_lds(                                  \
                (const __attribute__((address_space(1))) void*)(_s + 3072),    \
                (__attribute__((address_space(3))) void*)(_d + 3072), 16, 0, 0);\
        }                                                                      \
    } while (0)

__global__ __launch_bounds__(BLOCK, 8) void value_model_kernel(
    const float* __restrict__ act,      // [B, 59]
    const int*   __restrict__ cards,    // [B, 4, 3] int32
    const float* __restrict__ W,        // [12, 59]
    const float* __restrict__ bias,     // [12]
    float* __restrict__ out)            // [B, 4]
{
    // 4*3808 + 4352 = 19584 B -> 8 blocks/CU, 32 waves/CU.
    __shared__ float aLds[WAVES * TILE_STRIDE_F];
    __shared__ float xLds[WL_FLOATS];   // setup: padded W image; steady: fv[4][192]

    const int tid  = threadIdx.x;
    const int wave = tid >> 6;
    const int lane = tid & 63;
    float* tw = aLds + wave * TILE_STRIDE_F;

    // ---- one-time setup (raw barriers + lgkm fences only: vmcnt untouched) --
    for (int i = tid; i < WL_FLOATS; i += BLOCK) xLds[i] = 0.0f;       // zero W image
    if (lane < TILE_STRIDE_F - TILE_F) tw[TILE_F + lane] = 0.0f;       // zero act pad
    asm volatile("s_waitcnt lgkmcnt(0)" ::: "memory");
    __builtin_amdgcn_s_barrier();

    for (int i = tid; i < N_VALUES * N_IN; i += BLOCK) {               // scatter W
        int v = i / N_IN;
        int j = i - v * N_IN;
        xLds[v * WL_STRIDE + j] = W[i];
    }
    asm volatile("s_waitcnt lgkmcnt(0)" ::: "memory");
    __builtin_amdgcn_s_barrier();

    // per-lane B-fragments: lane l holds B[k=(l>>4)*8+e][col=l&15], K-half h.
    // v>=12 / k>=59 read zeros from the padded image -> frag zero-padded.
    const int colA = lane & 15, gA = lane >> 4;
    bf16x8 bf0, bf1;
    {
        const float* wp = xLds + colA * WL_STRIDE + gA * 8;
        #pragma unroll
        for (int e = 0; e < 8; ++e) bf0[e] = (__bf16)wp[e];
        #pragma unroll
        for (int e = 0; e < 8; ++e) bf1[e] = (__bf16)wp[32 + e];
    }
    float bv = 0.0f;
    if (colA < N_VALUES) bv = bias[colA];
    asm volatile("s_waitcnt lgkmcnt(0)" ::: "memory");
    __builtin_amdgcn_s_barrier();       // xLds now safe to reuse as fv

    float* fw = xLds + wave * (WROWS * FV_STRIDE);
    const int r4 = lane >> 2, c4 = lane & 3;

    // ---- 5-tile pipeline: stage(t+1)+cards(t+1) issued under tile t's tail --
    long t = (long)blockIdx.x * WAVES + wave;
    int ca, cb, cc;
    {
        const int* cp = cards + (t * WROWS + r4) * 12 + c4 * 3;
        ca = cp[0]; cb = cp[1]; cc = cp[2];
    }
    STAGE(t);

    #pragma unroll
    for (int it = 0; it < TPW; ++it) {
        asm volatile("s_waitcnt vmcnt(0) lgkmcnt(0)" ::: "memory");
        __builtin_amdgcn_wave_barrier();

        // A-frags from LDS (word stride 59, odd -> <=2 lanes/bank = free)
        bf16x8 a0, a1;
        const float* p = tw + colA * N_IN + gA * 8;
        #pragma unroll
        for (int e = 0; e < 8; ++e) a0[e] = (__bf16)p[e];
        #pragma unroll
        for (int e = 0; e < 8; ++e) a1[e] = (__bf16)p[32 + e];

        f32x4 acc = {bv, bv, bv, bv};
        acc = __builtin_amdgcn_mfma_f32_16x16x32_bf16(a0, bf0, acc, 0, 0, 0);
        acc = __builtin_amdgcn_mfma_f32_16x16x32_bf16(a1, bf1, acc, 0, 0, 0);

        // prefetch next tile NOW: compiler's lgkm wait before the MFMAs has
        // already ordered the a0/a1 ds_reads ahead of this DMA rewrite of tw.
        long tn = t + TOTWAVES;
        int na = 0, nb = 0, nc = 0;
        if (it + 1 < TPW) {
            STAGE(tn);
            const int* cp = cards + (tn * WROWS + r4) * 12 + c4 * 3;
            na = cp[0]; nb = cp[1]; nc = cp[2];
        }

        // C[row=(l>>4)*4+j][col=l&15] -> fv [16][12]
        if (colA < N_VALUES) {
            #pragma unroll
            for (int j = 0; j < 4; ++j)
                fw[(gA * 4 + j) * FV_STRIDE + colA] = acc[j];
        }
        asm volatile("s_waitcnt lgkmcnt(0)" ::: "memory");
        __builtin_amdgcn_wave_barrier();

        // gather: 1 card (3 indices) per lane, contiguous dword store
        const float* fv = fw + r4 * FV_STRIDE;
        long grow = t * WROWS + r4;
        out[grow * 4 + c4] = fv[ca] + fv[cb] + fv[cc];

        ca = na; cb = nb; cc = nc; t = tn;
    }
}

extern "C" void kernel_launch(void* const* d_in, const int* in_sizes, int n_in,
                              void* d_out, int out_size, void* d_ws, size_t ws_size,
                              hipStream_t stream) {
    const float* act   = (const float*)d_in[0];
    const int*   cards = (const int*)d_in[1];
    const float* W     = (const float*)d_in[2];
    const float* bias  = (const float*)d_in[3];
    float* out = (float*)d_out;

    value_model_kernel<<<GRID, BLOCK, 0, stream>>>(act, cards, W, bias, out);
}